// Round 1
// baseline (873.763 us; speedup 1.0000x reference)
//
#include <hip/hip_runtime.h>

#define S_LEN 2048
#define D_DIM 1024
#define H_DIM 4096
#define V_DIM 32000
#define B_SZ  4

typedef float  f32x4  __attribute__((ext_vector_type(4)));
typedef __bf16 bf16x8 __attribute__((ext_vector_type(8)));

__device__ __forceinline__ ushort f2bf(float f) {
    union { float f; unsigned u; } v; v.f = f;
    unsigned r = v.u + 0x7fffu + ((v.u >> 16) & 1u);
    return (ushort)(r >> 16);
}

// ---------------------------------------------------------------------------
// Weight transpose + fp32->bf16 convert: in fp32 [R][C] -> out bf16 [C][R]
// ---------------------------------------------------------------------------
__global__ void bt_wtranspose(const float* __restrict__ in, ushort* __restrict__ out,
                              int R, int C) {
    __shared__ ushort s[64][65];
    int r0 = blockIdx.y * 64, c0 = blockIdx.x * 64;
    int t = threadIdx.x;
    int lr = t >> 2, lc4 = (t & 3) * 16;
    const float* src = in + (size_t)(r0 + lr) * C + c0 + lc4;
#pragma unroll
    for (int j = 0; j < 4; ++j) {
        float4 v = ((const float4*)src)[j];
        s[lr][lc4 + 4 * j + 0] = f2bf(v.x);
        s[lr][lc4 + 4 * j + 1] = f2bf(v.y);
        s[lr][lc4 + 4 * j + 2] = f2bf(v.z);
        s[lr][lc4 + 4 * j + 3] = f2bf(v.w);
    }
    __syncthreads();
    int oc = t >> 2, orr = (t & 3) * 16;
    ushort tmp[16] __attribute__((aligned(16)));
#pragma unroll
    for (int j = 0; j < 16; ++j) tmp[j] = s[orr + j][oc];
    ushort* dst = out + (size_t)(c0 + oc) * R + r0 + orr;
    *(uint4*)dst        = *(uint4*)tmp;
    *(uint4*)(dst + 8)  = *(uint4*)(tmp + 8);
}

// ---------------------------------------------------------------------------
// Embedding + positional encoding: h = emb[tok] + pe  (fp32 master + bf16 copy)
// ---------------------------------------------------------------------------
__global__ void bt_embed(const int* __restrict__ tokens, const float* __restrict__ emb,
                         const float* __restrict__ pe, float* __restrict__ h,
                         ushort* __restrict__ hbf) {
    int row = blockIdx.x;                // 0..B*S-1
    int s   = row & (S_LEN - 1);
    int tok = tokens[row];
    int t   = threadIdx.x;               // 256 threads * 4 floats
    float4 v = ((const float4*)(emb + (size_t)tok * D_DIM))[t];
    float4 p = ((const float4*)(pe + (size_t)s * D_DIM))[t];
    v.x += p.x; v.y += p.y; v.z += p.z; v.w += p.w;
    ((float4*)(h + (size_t)row * D_DIM))[t] = v;
    uint2 pk;
    pk.x = (unsigned)f2bf(v.x) | ((unsigned)f2bf(v.y) << 16);
    pk.y = (unsigned)f2bf(v.z) | ((unsigned)f2bf(v.w) << 16);
    ((uint2*)(hbf + (size_t)row * D_DIM))[t] = pk;
}

// ---------------------------------------------------------------------------
// Templated B^T GEMM: C[m][n] = sum_k A[m][k] * B[n][k]   (A,B bf16, acc fp32)
// 128x128 tile, BK=64, 4 waves (2x2), mfma 16x16x32, global_load_lds staging,
// XOR-swizzled LDS (pre-swizzled global source, swizzled ds_read).
// ---------------------------------------------------------------------------
#define EPI_F32  0
#define EPI_BF16 1
#define EPI_RELU 2
#define EPI_RES  3

template <int EPI, bool CSKIP, bool KLIM>
__global__ __launch_bounds__(256, 2)
void bt_gemm(const ushort* __restrict__ A, const ushort* __restrict__ B,
             float* __restrict__ Cf, ushort* __restrict__ Cb,
             const float* __restrict__ Res,
             int lda, int ldb, int ldc, int K,
             size_t strideA, size_t strideB, size_t strideC) {
    int bm = blockIdx.y, bn = blockIdx.x;
    if (CSKIP && bn > bm) return;   // causal: skip tiles entirely above diagonal

    __shared__ ushort sA[128 * 64];
    __shared__ ushort sB[128 * 64];

    const int tid  = threadIdx.x;
    const int lane = tid & 63;
    const int wv   = tid >> 6;
    const int wr   = wv >> 1, wc = wv & 1;
    const int r15  = lane & 15, r4 = lane >> 4;

    const ushort* Ab = A + strideA * blockIdx.z + (size_t)bm * 128 * lda;
    const ushort* Bb = B + strideB * blockIdx.z + (size_t)bn * 128 * ldb;

    int ktiles = K >> 6;
    if (KLIM) { int lim = (bm + 1) * 2; if (lim < ktiles) ktiles = lim; }

    f32x4 acc[4][4];
#pragma unroll
    for (int m = 0; m < 4; ++m)
#pragma unroll
        for (int n = 0; n < 4; ++n) acc[m][n] = (f32x4){0.f, 0.f, 0.f, 0.f};

    const int srow = wv * 8 + (lane >> 3);  // row within a 32-row staging round
    const int sout = lane & 7;              // destination 16B slot within row

    for (int kt = 0; kt < ktiles; ++kt) {
        __syncthreads();                    // protect LDS from overwrite
        const ushort* Ak = Ab + kt * 64;
        const ushort* Bk = Bb + kt * 64;
#pragma unroll
        for (int j = 0; j < 4; ++j) {
            int row = j * 32 + srow;
            int si  = sout ^ (row & 7);     // pre-swizzled global source slot
            __builtin_amdgcn_global_load_lds(
                (const __attribute__((address_space(1))) void*)(Ak + (size_t)row * lda + si * 8),
                (__attribute__((address_space(3))) void*)(sA + j * 2048 + wv * 512), 16, 0, 0);
        }
#pragma unroll
        for (int j = 0; j < 4; ++j) {
            int row = j * 32 + srow;
            int si  = sout ^ (row & 7);
            __builtin_amdgcn_global_load_lds(
                (const __attribute__((address_space(1))) void*)(Bk + (size_t)row * ldb + si * 8),
                (__attribute__((address_space(3))) void*)(sB + j * 2048 + wv * 512), 16, 0, 0);
        }
        __syncthreads();                    // drains vmcnt + barrier
#pragma unroll
        for (int kk = 0; kk < 2; ++kk) {
            bf16x8 af[4], bv[4];
            int s = kk * 4 + r4;
#pragma unroll
            for (int m = 0; m < 4; ++m) {
                int row = wr * 64 + m * 16 + r15;
                af[m] = *(const bf16x8*)(sA + (size_t)row * 64 + (size_t)((s ^ (row & 7)) * 8));
            }
#pragma unroll
            for (int n = 0; n < 4; ++n) {
                int col = wc * 64 + n * 16 + r15;
                bv[n] = *(const bf16x8*)(sB + (size_t)col * 64 + (size_t)((s ^ (col & 7)) * 8));
            }
#pragma unroll
            for (int m = 0; m < 4; ++m)
#pragma unroll
                for (int n = 0; n < 4; ++n)
                    acc[m][n] = __builtin_amdgcn_mfma_f32_16x16x32_bf16(af[m], bv[n], acc[m][n], 0, 0, 0);
        }
    }

    // epilogue: D[i][j] -> row = 4*(lane>>4)+r, col = lane&15
    size_t cz = strideC * blockIdx.z;
    int rowb = bm * 128 + wr * 64 + r4 * 4;
    int colb = bn * 128 + wc * 64 + r15;
#pragma unroll
    for (int m = 0; m < 4; ++m) {
#pragma unroll
        for (int r = 0; r < 4; ++r) {
            int row = rowb + m * 16 + r;
            size_t base = cz + (size_t)row * ldc + colb;
#pragma unroll
            for (int n = 0; n < 4; ++n) {
                float v = acc[m][n][r];
                size_t idx = base + n * 16;
                if (EPI == EPI_F32)       Cf[idx] = v;
                else if (EPI == EPI_BF16) Cb[idx] = f2bf(v);
                else if (EPI == EPI_RELU) Cb[idx] = f2bf(fmaxf(v, 0.f));
                else { float o = v + Res[idx]; Cf[idx] = o; Cb[idx] = f2bf(o); }
            }
        }
    }
}

// ---------------------------------------------------------------------------
// Causal row softmax: scores fp32 [B][S][S] -> probs bf16 (zeros above diag)
// ---------------------------------------------------------------------------
__device__ __forceinline__ float wred_max(float v) {
#pragma unroll
    for (int off = 32; off; off >>= 1) v = fmaxf(v, __shfl_xor(v, off));
    return v;
}
__device__ __forceinline__ float wred_sum(float v) {
#pragma unroll
    for (int off = 32; off; off >>= 1) v += __shfl_xor(v, off);
    return v;
}

__global__ void bt_softmax(const float* __restrict__ scores, ushort* __restrict__ probs) {
    int row = blockIdx.x;                 // b*S + s
    int s   = row & (S_LEN - 1);
    const float* src = scores + (size_t)row * S_LEN;
    ushort*      dst = probs  + (size_t)row * S_LEN;
    int tid = threadIdx.x;
    int nvalid = s + 1;

    float vals[8];
    float mx = -1e30f;
#pragma unroll
    for (int j = 0; j < 8; ++j) {
        int t = tid + j * 256;
        float v = (t < nvalid) ? src[t] * 0.03125f : -1e30f;  // scale 1/sqrt(1024)
        vals[j] = v;
        mx = fmaxf(mx, v);
    }
    __shared__ float red[4], red2[4];
    mx = wred_max(mx);
    if ((tid & 63) == 0) red[tid >> 6] = mx;
    __syncthreads();
    mx = fmaxf(fmaxf(red[0], red[1]), fmaxf(red[2], red[3]));

    float sum = 0.f, ps[8];
#pragma unroll
    for (int j = 0; j < 8; ++j) {
        float p = exp2f((vals[j] - mx) * 1.44269504f);
        ps[j] = p; sum += p;
    }
    sum = wred_sum(sum);
    if ((tid & 63) == 0) red2[tid >> 6] = sum;
    __syncthreads();
    sum = red2[0] + red2[1] + red2[2] + red2[3];
    float inv = 1.0f / sum;
#pragma unroll
    for (int j = 0; j < 8; ++j) {
        int t = tid + j * 256;
        dst[t] = (t < nvalid) ? f2bf(ps[j] * inv) : (ushort)0;
    }
}

// ---------------------------------------------------------------------------
// Last-token logits: out[b][v] = sum_d h[b*S+S-1][d] * w_out[d][v]   (fp32)
// grid (V/256, 8 d-chunks); atomic accumulate into zeroed d_out.
// ---------------------------------------------------------------------------
__global__ void bt_logits(const float* __restrict__ h, const float* __restrict__ wout,
                          float* __restrict__ out) {
    __shared__ float hl[4][128];
    int tid = threadIdx.x;
    int d0 = blockIdx.y * 128;
    if (tid < 128) {
#pragma unroll
        for (int b = 0; b < 4; ++b)
            hl[b][tid] = h[((size_t)b * S_LEN + (S_LEN - 1)) * D_DIM + d0 + tid];
    }
    __syncthreads();
    int v = blockIdx.x * 256 + tid;
    float a0 = 0, a1 = 0, a2 = 0, a3 = 0;
    for (int j = 0; j < 128; ++j) {
        float w = wout[(size_t)(d0 + j) * V_DIM + v];
        a0 += hl[0][j] * w; a1 += hl[1][j] * w;
        a2 += hl[2][j] * w; a3 += hl[3][j] * w;
    }
    atomicAdd(out + v, a0);
    atomicAdd(out + V_DIM + v, a1);
    atomicAdd(out + 2 * V_DIM + v, a2);
    atomicAdd(out + 3 * V_DIM + v, a3);
}

// ---------------------------------------------------------------------------
extern "C" void kernel_launch(void* const* d_in, const int* in_sizes, int n_in,
                              void* d_out, int out_size, void* d_ws, size_t ws_size,
                              hipStream_t stream) {
    const int*   tokens = (const int*)d_in[0];
    const float* emb    = (const float*)d_in[1];
    const float* pe     = (const float*)d_in[2];
    const float* wgt[10];
    for (int i = 0; i < 10; ++i) wgt[i] = (const float*)d_in[3 + i];
    const float* wout = (const float*)d_in[13];

    char* w = (char*)d_ws;
    size_t o = 0;
    auto take = [&](size_t sz) { char* p = w + o; o += (sz + 255) & ~(size_t)255; return p; };

    const size_t DD = (size_t)D_DIM * D_DIM * 2;   // 2 MiB
    const size_t DH = (size_t)D_DIM * H_DIM * 2;   // 8 MiB
    size_t wsz[10] = {DD, DD, DD, DH, DH, DD, DD, DD, DH, DH};
    ushort* wT[10];
    for (int i = 0; i < 10; ++i) wT[i] = (ushort*)take(wsz[i]);

    const size_t NROW = (size_t)B_SZ * S_LEN;      // 8192
    float*  h0     = (float*)take(NROW * D_DIM * 4);
    float*  h1     = (float*)take(NROW * D_DIM * 4);
    ushort* hbf    = (ushort*)take(NROW * D_DIM * 2);
    ushort* hresbf = (ushort*)take(NROW * D_DIM * 2);
    ushort* xkbf   = (ushort*)take(NROW * D_DIM * 2);
    ushort* xvt    = (ushort*)take((size_t)D_DIM * NROW * 2);
    ushort* hattn  = (ushort*)take(NROW * D_DIM * 2);
    char*   G      = take((size_t)B_SZ * S_LEN * S_LEN * 4 + (size_t)B_SZ * S_LEN * S_LEN * 2);
    float*  scores = (float*)G;
    ushort* probs  = (ushort*)(G + (size_t)B_SZ * S_LEN * S_LEN * 4);
    ushort* tbf    = (ushort*)G;   // FFN hidden aliases scores (disjoint phases)

    // 1) transpose+convert weights to bf16 [N][K]
    int wR[10] = {1024, 1024, 1024, 1024, 4096, 1024, 1024, 1024, 1024, 4096};
    int wC[10] = {1024, 1024, 1024, 4096, 1024, 1024, 1024, 1024, 4096, 1024};
    for (int i = 0; i < 10; ++i)
        bt_wtranspose<<<dim3(wC[i] / 64, wR[i] / 64), 256, 0, stream>>>(wgt[i], wT[i], wR[i], wC[i]);

    // 2) embedding
    bt_embed<<<NROW, 256, 0, stream>>>(tokens, emb, pe, h0, hbf);

    // 3) transformer layers
    auto layer = [&](ushort* wk, ushort* wv2, ushort* wo, ushort* w1, ushort* w2) {
        // xk = h @ wk
        bt_gemm<EPI_BF16, false, false><<<dim3(8, 64, 1), 256, 0, stream>>>(
            hbf, wk, nullptr, xkbf, nullptr, D_DIM, D_DIM, D_DIM, D_DIM, 0, 0, 0);
        // xv^T = wv^T @ h^T   -> [D][B*S]
        bt_gemm<EPI_BF16, false, false><<<dim3(64, 8, 1), 256, 0, stream>>>(
            wv2, hbf, nullptr, xvt, nullptr, D_DIM, D_DIM, (int)NROW, D_DIM, 0, 0, 0);
        // scores = Q @ K^T per batch (causal tiles only), raw fp32
        bt_gemm<EPI_F32, true, false><<<dim3(16, 16, B_SZ), 256, 0, stream>>>(
            hbf, xkbf, scores, nullptr, nullptr, D_DIM, D_DIM, S_LEN, D_DIM,
            (size_t)S_LEN * D_DIM, (size_t)S_LEN * D_DIM, (size_t)S_LEN * S_LEN);
        // softmax rows (scale + causal), bf16 probs zero-padded
        bt_softmax<<<NROW, 256, 0, stream>>>(scores, probs);
        // h_attn = probs @ xv  (B^T = xv^T), K-limited by causality
        bt_gemm<EPI_BF16, false, true><<<dim3(8, 16, B_SZ), 256, 0, stream>>>(
            probs, xvt, nullptr, hattn, nullptr, S_LEN, (int)NROW, D_DIM, S_LEN,
            (size_t)S_LEN * S_LEN, (size_t)S_LEN, (size_t)S_LEN * D_DIM);
        // h_res = h + h_attn @ wo   (fp32 master h1 + bf16 copy)
        bt_gemm<EPI_RES, false, false><<<dim3(8, 64, 1), 256, 0, stream>>>(
            hattn, wo, h1, hresbf, h0, D_DIM, D_DIM, D_DIM, D_DIM, 0, 0, 0);
        // t = relu(h_res @ w1)
        bt_gemm<EPI_RELU, false, false><<<dim3(32, 64, 1), 256, 0, stream>>>(
            hresbf, w1, nullptr, tbf, nullptr, D_DIM, D_DIM, H_DIM, D_DIM, 0, 0, 0);
        // h = h_res + t @ w2   (fp32 h0 + bf16 hbf for next layer)
        bt_gemm<EPI_RES, false, false><<<dim3(8, 64, 1), 256, 0, stream>>>(
            tbf, w2, h0, hbf, h1, H_DIM, H_DIM, D_DIM, H_DIM, 0, 0, 0);
    };
    layer(wT[0], wT[1], wT[2], wT[3], wT[4]);
    layer(wT[5], wT[6], wT[7], wT[8], wT[9]);

    // 4) last-token logits (fp32)
    hipMemsetAsync(d_out, 0, (size_t)B_SZ * V_DIM * sizeof(float), stream);
    bt_logits<<<dim3(V_DIM / 256, D_DIM / 128), 256, 0, stream>>>(h0, wout, (float*)d_out);
}